// Round 5
// baseline (63.609 us; speedup 1.0000x reference)
//
#include <hip/hip_runtime.h>

// B=8, N=1e6 vertices/batch, vertex = 6 f32. out = [T@p/w, normalize(R@n)].
// Memory-bound. Pipelined persistent blocks: 9 tiles/block, double-buffered
// LDS, async global->LDS DMA with COUNTED vmcnt waits (never drain to 0 in
// the loop) + raw s_barrier, NT stores (keep the 192MB input L3-resident).

constexpr int TPB     = 256;
constexpr int F4PT    = 3;            // float4 per thread per tile (2 verts)
constexpr int TILE_F4 = TPB * F4PT;   // 768 float4 = 12 KB
constexpr int TPBLK   = 9;            // tiles per pipelined block (1953=217*9)

typedef const __attribute__((address_space(1))) void* gp_t;
typedef __attribute__((address_space(3))) void*       lp_t;
typedef float __attribute__((ext_vector_type(4)))     f32x4;

__device__ __forceinline__ void xform_pair(const float4& r0, const float4& r1,
                                           const float4& r2, const float4& r3,
                                           float4& q0, float4& q1, float4& q2)
{
    float o[12];
#pragma unroll
    for (int v = 0; v < 2; ++v) {
        float px, py, pz, nx, ny, nz;
        if (v == 0) { px = q0.x; py = q0.y; pz = q0.z; nx = q0.w; ny = q1.x; nz = q1.y; }
        else        { px = q1.z; py = q1.w; pz = q2.x; nx = q2.y; ny = q2.z; nz = q2.w; }
        float tx = r0.x*px + r0.y*py + r0.z*pz + r0.w;
        float ty = r1.x*px + r1.y*py + r1.z*pz + r1.w;
        float tz = r2.x*px + r2.y*py + r2.z*pz + r2.w;
        float tw = r3.x*px + r3.y*py + r3.z*pz + r3.w;
        float invw = 1.0f / tw;
        tx *= invw; ty *= invw; tz *= invw;
        float mx = r0.x*nx + r0.y*ny + r0.z*nz;
        float my = r1.x*nx + r1.y*ny + r1.z*nz;
        float mz = r2.x*nx + r2.y*ny + r2.z*nz;
        float len = fmaxf(sqrtf(mx*mx + my*my + mz*mz), 1e-8f);
        float inv = 1.0f / len;
        mx *= inv; my *= inv; mz *= inv;
        o[v*6+0] = tx; o[v*6+1] = ty; o[v*6+2] = tz;
        o[v*6+3] = mx; o[v*6+4] = my; o[v*6+5] = mz;
    }
    q0 = make_float4(o[0], o[1], o[2],  o[3]);
    q1 = make_float4(o[4], o[5], o[6],  o[7]);
    q2 = make_float4(o[8], o[9], o[10], o[11]);
}

__global__ __launch_bounds__(TPB)
void GPUBatchProcessor_68186900791881_kernel(const float4* __restrict__ vin,
                                             const float* __restrict__ xf,
                                             float4* __restrict__ vout,
                                             int f4_per_batch,
                                             int pipe_blocks)
{
    __shared__ float4 lds[2][TILE_F4];
    const int t = threadIdx.x;
    const int b = blockIdx.y;                    // wave-uniform batch
    const long long batchBase = (long long)b * f4_per_batch;
    const float4* src = vin + batchBase;
    float4*       dst = vout + batchBase;

    const float4* T4 = reinterpret_cast<const float4*>(xf) + (size_t)b * 4;
    const float4 r0 = T4[0], r1 = T4[1], r2 = T4[2], r3 = T4[3];

    if (blockIdx.x < pipe_blocks) {
        const long long tile0 = (long long)blockIdx.x * TPBLK;
        // prologue: stage tile 0 into buf 0
        {
            const float4* s = src + tile0 * TILE_F4;
#pragma unroll
            for (int k = 0; k < F4PT; ++k)
                __builtin_amdgcn_global_load_lds((gp_t)(s + k*TPB + t),
                                                 (lp_t)&lds[0][k*TPB + t], 16, 0, 0);
        }
#pragma unroll
        for (int i = 0; i < TPBLK; ++i) {
            const int cur = i & 1;
            if (i + 1 < TPBLK) {                 // prefetch tile i+1 into buf cur^1
                const float4* s = src + (tile0 + i + 1) * TILE_F4;
#pragma unroll
                for (int k = 0; k < F4PT; ++k)
                    __builtin_amdgcn_global_load_lds((gp_t)(s + k*TPB + t),
                                                     (lp_t)&lds[cur ^ 1][k*TPB + t], 16, 0, 0);
            }
            // counted wait: oldest 3 (tile i's loads) done; newer loads/stores stay in flight
            if (i == 0 || i + 1 == TPBLK) asm volatile("s_waitcnt vmcnt(3)" ::: "memory");
            else                          asm volatile("s_waitcnt vmcnt(6)" ::: "memory");
            __builtin_amdgcn_s_barrier();        // all waves have tile i
            __builtin_amdgcn_sched_barrier(0);

            float4 q0 = lds[cur][t*3 + 0];
            float4 q1 = lds[cur][t*3 + 1];
            float4 q2 = lds[cur][t*3 + 2];
            xform_pair(r0, r1, r2, r3, q0, q1, q2);
            lds[cur][t*3 + 0] = q0;              // in-place (same-thread slots)
            lds[cur][t*3 + 1] = q1;
            lds[cur][t*3 + 2] = q2;

            asm volatile("s_waitcnt lgkmcnt(0)" ::: "memory");  // drain my LDS ops
            __builtin_amdgcn_s_barrier();        // results visible to all waves
            __builtin_amdgcn_sched_barrier(0);

            const long long tb = (tile0 + i) * TILE_F4;
            const f32x4* l = reinterpret_cast<const f32x4*>(&lds[cur][0]);
            f32x4* d = reinterpret_cast<f32x4*>(dst + tb);
#pragma unroll
            for (int k = 0; k < F4PT; ++k)
                __builtin_nontemporal_store(l[k*TPB + t], d + k*TPB + t);
        }
    } else {
        // tail: simple guarded path over [pipe coverage, f4_per_batch)
        const long long tailStart = (long long)pipe_blocks * TPBLK * TILE_F4;
        const int nTail = gridDim.x - pipe_blocks;
        for (long long base = tailStart + (long long)(blockIdx.x - pipe_blocks) * TILE_F4;
             base < f4_per_batch;
             base += (long long)nTail * TILE_F4) {
            int rem = (int)(f4_per_batch - base); if (rem > TILE_F4) rem = TILE_F4;
            __syncthreads();                     // guard LDS reuse across chunks
#pragma unroll
            for (int k = 0; k < F4PT; ++k) {
                int f = k*TPB + t;
                if (f < rem) lds[0][f] = src[base + f];
            }
            __syncthreads();
            const int npairs = rem / F4PT;       // <= 256
            if (t < npairs) {
                float4 q0 = lds[0][t*3 + 0];
                float4 q1 = lds[0][t*3 + 1];
                float4 q2 = lds[0][t*3 + 2];
                xform_pair(r0, r1, r2, r3, q0, q1, q2);
                lds[0][t*3 + 0] = q0;
                lds[0][t*3 + 1] = q1;
                lds[0][t*3 + 2] = q2;
            }
            __syncthreads();
#pragma unroll
            for (int k = 0; k < F4PT; ++k) {
                int f = k*TPB + t;
                if (f < rem) dst[base + f] = lds[0][f];
            }
        }
    }
}

extern "C" void kernel_launch(void* const* d_in, const int* in_sizes, int n_in,
                              void* d_out, int out_size, void* d_ws, size_t ws_size,
                              hipStream_t stream) {
    const float* verts = (const float*)d_in[0];   // (B,N,6) f32
    // d_in[1] = batch_indices — unused by the reference
    const float* xf    = (const float*)d_in[2];   // (B,4,4) f32
    float*       out   = (float*)d_out;           // (B,N,6) f32

    const int B = in_sizes[2] / 16;
    const long long totalV = (long long)in_sizes[0] / 6;
    const int N = (int)(totalV / B);              // 1e6
    const int f4_per_batch = N * 6 / 4;           // 1.5e6

    const int full_tiles  = f4_per_batch / TILE_F4;   // 1953
    const int pipe_blocks = full_tiles / TPBLK;       // 217 (exact: 1953=217*9)
    // 1 tail block per batch covers leftover full tiles (none here) + 96 f4.

    dim3 grid(pipe_blocks + 1, B);
    GPUBatchProcessor_68186900791881_kernel<<<grid, TPB, 0, stream>>>(
        reinterpret_cast<const float4*>(verts), xf,
        reinterpret_cast<float4*>(out), f4_per_batch, pipe_blocks);
}

// Round 6
// 60.178 us; speedup vs baseline: 1.0570x; 1.0570x over previous
//
#include <hip/hip_runtime.h>

// B=8, N=1e6 vertices/batch, vertex = 6 f32 (pos.xyz, nrm.xyz).
// out[b,n] = [ (T@[p,1]).xyz / w , normalize(R@n) ], R = T[:3,:3].
// Memory-bound (384 MB irreducible). Staging: async global->LDS DMA
// (global_load_lds w16, lane-contiguous float4 dest); compute reads the
// 48B-stride pattern from LDS (~conflict-free); stores staged back through
// LDS as lane-contiguous nontemporal 16B. Service rate ~6.4 TB/s = r+w copy
// ceiling; R5's deeper pipeline regressed (occupancy), so this structure is
// the keeper.

constexpr int TPB     = 256;
constexpr int F4PT    = 3;            // float4s per thread (= 2 vertices)
constexpr int TILE_F4 = TPB * F4PT;   // 768 float4 = 512 vertices = 12 KB

typedef const __attribute__((address_space(1))) void* gp_t;   // global
typedef __attribute__((address_space(3))) void*       lp_t;   // LDS
typedef float __attribute__((ext_vector_type(4)))     f32x4;  // native vec4

__global__ __launch_bounds__(TPB)
void GPUBatchProcessor_68186900791881_kernel(const float4* __restrict__ vin,
                                             const float* __restrict__ xf,
                                             float4* __restrict__ vout,
                                             int f4_per_batch,    // N*6/4
                                             int pairs_per_batch) // N/2
{
    __shared__ float4 lds[TILE_F4];
    const int t = threadIdx.x;
    const int b = blockIdx.y;                       // wave-uniform batch
    const long long batchBase = (long long)b * f4_per_batch;
    const int tileF4 = blockIdx.x * TILE_F4;

    // ---- async staged load: global->LDS DMA, lane-contiguous float4 ----
    const float4* src = vin + batchBase;
#pragma unroll
    for (int k = 0; k < F4PT; ++k) {
        int f = tileF4 + k * TPB + t;
        if (f < f4_per_batch) {
            __builtin_amdgcn_global_load_lds((gp_t)(src + f),
                                             (lp_t)&lds[k * TPB + t],
                                             16, 0, 0);
        }
    }
    __syncthreads();   // drains vmcnt: all DMA loads landed

    // transform rows (b uniform -> scalar loads)
    const float4* T = reinterpret_cast<const float4*>(xf) + (size_t)b * 4;
    const float4 r0 = T[0], r1 = T[1], r2 = T[2], r3 = T[3];

    const int p = blockIdx.x * TPB + t;             // pair index within batch
    if (p < pairs_per_batch) {
        const float4 q0 = lds[t * 3 + 0];
        const float4 q1 = lds[t * 3 + 1];
        const float4 q2 = lds[t * 3 + 2];

        float o[12];
#pragma unroll
        for (int v = 0; v < 2; ++v) {
            float px, py, pz, nx, ny, nz;
            if (v == 0) { px = q0.x; py = q0.y; pz = q0.z; nx = q0.w; ny = q1.x; nz = q1.y; }
            else        { px = q1.z; py = q1.w; pz = q2.x; nx = q2.y; ny = q2.z; nz = q2.w; }

            float tx = r0.x * px + r0.y * py + r0.z * pz + r0.w;
            float ty = r1.x * px + r1.y * py + r1.z * pz + r1.w;
            float tz = r2.x * px + r2.y * py + r2.z * pz + r2.w;
            float tw = r3.x * px + r3.y * py + r3.z * pz + r3.w;
            float invw = 1.0f / tw;
            tx *= invw; ty *= invw; tz *= invw;

            float mx = r0.x * nx + r0.y * ny + r0.z * nz;
            float my = r1.x * nx + r1.y * ny + r1.z * nz;
            float mz = r2.x * nx + r2.y * ny + r2.z * nz;
            float len = fmaxf(sqrtf(mx * mx + my * my + mz * mz), 1e-8f);
            float inv = 1.0f / len;
            mx *= inv; my *= inv; mz *= inv;

            o[v * 6 + 0] = tx; o[v * 6 + 1] = ty; o[v * 6 + 2] = tz;
            o[v * 6 + 3] = mx; o[v * 6 + 4] = my; o[v * 6 + 5] = mz;
        }

        lds[t * 3 + 0] = make_float4(o[0], o[1], o[2],  o[3]);
        lds[t * 3 + 1] = make_float4(o[4], o[5], o[6],  o[7]);
        lds[t * 3 + 2] = make_float4(o[8], o[9], o[10], o[11]);
    }
    __syncthreads();

    // ---- staged store: lane-contiguous nontemporal 16B ----
    f32x4* dst = reinterpret_cast<f32x4*>(vout + batchBase);
    const f32x4* lsrc = reinterpret_cast<const f32x4*>(lds);
#pragma unroll
    for (int k = 0; k < F4PT; ++k) {
        int f = tileF4 + k * TPB + t;
        if (f < f4_per_batch)
            __builtin_nontemporal_store(lsrc[k * TPB + t], dst + f);
    }
}

extern "C" void kernel_launch(void* const* d_in, const int* in_sizes, int n_in,
                              void* d_out, int out_size, void* d_ws, size_t ws_size,
                              hipStream_t stream) {
    const float* verts = (const float*)d_in[0];   // (B,N,6) f32
    // d_in[1] = batch_indices — unused by the reference
    const float* xf    = (const float*)d_in[2];   // (B,4,4) f32
    float*       out   = (float*)d_out;           // (B,N,6) f32

    const int B = in_sizes[2] / 16;
    const long long totalV = (long long)in_sizes[0] / 6;
    const int N = (int)(totalV / B);              // 1e6
    const int f4_per_batch    = N * 6 / 4;        // 1.5e6
    const int pairs_per_batch = N / 2;            // 5e5

    const int tiles = (f4_per_batch + TILE_F4 - 1) / TILE_F4;  // 1954
    dim3 grid(tiles, B);
    GPUBatchProcessor_68186900791881_kernel<<<grid, TPB, 0, stream>>>(
        reinterpret_cast<const float4*>(verts), xf,
        reinterpret_cast<float4*>(out), f4_per_batch, pairs_per_batch);
}